// Round 19
// baseline (136.707 us; speedup 1.0000x reference)
//
#include <hip/hip_runtime.h>
#include <math.h>

// ---------------------------------------------------------------------------
// bf16-MFMA implementation, both layers merged (z=2), global_load_lds staging.
//  - all GEMMs 1-term plain bf16; qkv BM=128, FF BM=64 (R17-proven optimum)
//  - R19: attention QBLK=128 with m_ init = 0 (fixes R18's NaN on fully-
//    masked first k-tiles; online softmax is shift-invariant for finite m).
//  - qkv linear [z][4096][1536] output via permuted weight rows (R10)
//  - attention core: R12 att[2] pipeline (swapped QK^T, in-reg P, defer-max,
//    setprio), per-qf.
// ---------------------------------------------------------------------------

typedef float f32x4 __attribute__((ext_vector_type(4)));
typedef short s16x8 __attribute__((ext_vector_type(8)));
typedef int   i32x4 __attribute__((ext_vector_type(4)));
typedef unsigned short u16;
typedef unsigned int u32;

#define NTOK 1024
#define PL 512
#define QSCALE 0.04419417382415922f  // 1/sqrt(512)

__device__ inline u16 f2bf(float f) {
    unsigned u = __builtin_bit_cast(unsigned, f);
    unsigned r = u + 0x7fffu + ((u >> 16) & 1u);   // RNE
    return (u16)(r >> 16);
}
__device__ inline float bf2f(u16 h) {
    unsigned u = ((unsigned)h) << 16;
    return __builtin_bit_cast(float, u);
}
__device__ inline u32 cvtpk(float a, float b) {   // lo=a, hi=b (RNE)
    u32 r;
    asm("v_cvt_pk_bf16_f32 %0, %1, %2" : "=v"(r) : "v"(a), "v"(b));
    return r;
}

__device__ inline void gll16(const void* g, void* l) {
    __builtin_amdgcn_global_load_lds(
        (const __attribute__((address_space(1))) u32*)g,
        (__attribute__((address_space(3))) u32*)l, 16, 0, 0);
}

// ---------------------------------------------------------------------------
// Merged prep: blockIdx ranges -> {x->bf16, wqkv^T, w1^T, w2^T}
// ---------------------------------------------------------------------------
__global__ __launch_bounds__(256) void prep(const float* __restrict__ X,
    u16* __restrict__ xhi,
    const float* __restrict__ Wq0, const float* __restrict__ Wq1, u16* __restrict__ wqh,
    const float* __restrict__ W10, const float* __restrict__ W11, u16* __restrict__ w1h,
    const float* __restrict__ W20, const float* __restrict__ W21, u16* __restrict__ w2h)
{
    const int bid = blockIdx.x;
    if (bid < 2048) {
        const int i = (bid * 256 + threadIdx.x) * 4;
        float4 v = *(const float4*)&X[i];
        xhi[i + 0] = f2bf(v.x); xhi[i + 1] = f2bf(v.y);
        xhi[i + 2] = f2bf(v.z); xhi[i + 3] = f2bf(v.w);
        return;
    }
    const float* W;
    u16* Whi;
    int N, kx, ny;
    if (bid < 3584) {
        const int idx = bid - 2048;
        const int z = idx / 768, rem = idx % 768;
        kx = rem % 16; ny = rem / 16;
        W = z ? Wq1 : Wq0; Whi = wqh + (size_t)z * 786432; N = 1536;
    } else if (bid < 4096) {
        const int idx = bid - 3584;
        const int z = idx / 256, rem = idx % 256;
        kx = rem % 16; ny = rem / 16;
        W = z ? W11 : W10; Whi = w1h + (size_t)z * 262144; N = 512;
    } else {
        const int idx = bid - 4096;
        const int z = idx / 256, rem = idx % 256;
        kx = rem % 16; ny = rem / 16;
        W = z ? W21 : W20; Whi = w2h + (size_t)z * 262144; N = 512;
    }
    __shared__ float T[32][36];
    const int k0 = kx * 32, n0 = ny * 32;
    const int tr = threadIdx.x >> 3, tc = (threadIdx.x & 7) * 4;
    *(float4*)&T[tr][tc] = *(const float4*)&W[(size_t)(k0 + tr) * N + n0 + tc];
    __syncthreads();
    const size_t o = (size_t)(n0 + tr) * 512 + k0 + tc;
    #pragma unroll
    for (int j = 0; j < 4; j++) Whi[o + j] = f2bf(T[tc + j][tr]);
}

// π: permuted col j -> original col (head-fast split c2 = dd*8+h)
__device__ inline int qkv_perm(int j) {
    return (j >> 9) * 512 + ((j & 63) << 3) + ((j >> 6) & 7);
}

// ---------------------------------------------------------------------------
// 1-term bf16 MFMA GEMM, z = layer. A[4096][512] x Bt[N][512].
// EPI: 0 = qkv (B rows permuted, linear output, Q scaled),
//      1 = gelu -> bf16, 2 = plain bf16.
// BK=32; dbuf gll staging. Wave (wm,wn): rows [wm*BM/2,+BM/2) x cols [wn*64,+64).
// ---------------------------------------------------------------------------
template<int BM, int EPI>
__global__ __launch_bounds__(256) void gemm_mfma(
    const u16* __restrict__ AB, const size_t aLS,
    const u16* __restrict__ BB, const size_t bLS,
    const float* __restrict__ bias0, const float* __restrict__ bias1, const int Ncols,
    u16* __restrict__ oh0, u16* __restrict__ oh1)
{
    constexpr int FM = BM / 32;          // fragments per wave in M
    constexpr int WMS = BM / 2;          // wave M-stride
    __shared__ u16 Ah[2][BM * 32], Bh[2][128 * 32];
    const int z = blockIdx.z;
    const u16* A = AB + (size_t)z * aLS;
    const u16* B = BB + (size_t)z * bLS;
    const float* bias = z ? bias1 : bias0;
    u16* oh = z ? oh1 : oh0;

    const int t = threadIdx.x, l = t & 63, w = t >> 6;
    const int lr = l & 15, lg = l >> 4;
    const int wm = w >> 1, wn = w & 1;
    const int m0 = blockIdx.x * BM, n0 = blockIdx.y * 128;
    const int srow = l >> 2, sch = l & 3;    // staging lane coords (16 rows/KB)

    f32x4 acc[FM][4];
    #pragma unroll
    for (int i = 0; i < FM; i++)
        #pragma unroll
        for (int j = 0; j < 4; j++) acc[i][j] = f32x4{0.f, 0.f, 0.f, 0.f};

    auto stage = [&](int bufi, int k0) {
        for (int j = w; j < BM / 16; j += 4) {
            const int r = j * 16 + srow;
            const int ck = sch ^ ((r >> 1) & 3);
            gll16(&A[(size_t)(m0 + r) * 512 + k0 + ck * 8], &Ah[bufi][j * 512]);
        }
        for (int j = w; j < 8; j += 4) {
            const int r = j * 16 + srow;
            const int ck = sch ^ ((r >> 1) & 3);
            const int brow = (EPI == 0) ? qkv_perm(n0 + r) : (n0 + r);
            gll16(&B[(size_t)brow * 512 + k0 + ck * 8], &Bh[bufi][j * 512]);
        }
    };

    stage(0, 0);
    __syncthreads();
    int buf = 0;
    for (int kt = 0; kt < 16; kt++) {
        if (kt < 15) stage(buf ^ 1, (kt + 1) * 32);

        s16x8 ah[FM];
        #pragma unroll
        for (int fm = 0; fm < FM; fm++) {
            const int r = wm * WMS + fm * 16 + lr;
            ah[fm] = *(const s16x8*)&Ah[buf][r * 32 + ((lg ^ ((r >> 1) & 3)) << 3)];
        }
        #pragma unroll
        for (int fn = 0; fn < 4; fn++) {
            const int r = wn * 64 + fn * 16 + lr;
            s16x8 bh = *(const s16x8*)&Bh[buf][r * 32 + ((lg ^ ((r >> 1) & 3)) << 3)];
            #pragma unroll
            for (int fm = 0; fm < FM; fm++)
                acc[fm][fn] = __builtin_amdgcn_mfma_f32_16x16x32_bf16(ah[fm], bh, acc[fm][fn], 0, 0, 0);
        }
        __syncthreads();   // waves done with buf; stage(buf^1) drained
        buf ^= 1;
    }
    // epilogue: every wave writes its own (wm,wn) sub-tile
    #pragma unroll
    for (int fm = 0; fm < FM; fm++)
        #pragma unroll
        for (int fn = 0; fn < 4; fn++)
            #pragma unroll
            for (int rg = 0; rg < 4; rg++) {
                const int r = m0 + wm * WMS + fm * 16 + lg * 4 + rg;
                const int c = n0 + wn * 64 + fn * 16 + lr;
                if constexpr (EPI == 0) {
                    float v = acc[fm][fn][rg] + bias[qkv_perm(c)];
                    if (c < 512) v *= QSCALE;   // Q third (uniform per block)
                    oh[((size_t)z * 4096 + r) * Ncols + c] = f2bf(v);
                } else {
                    float gl = acc[fm][fn][rg] + bias[c];
                    if constexpr (EPI == 1)
                        gl = 0.5f * gl * (1.f + erff(gl * 0.70710678118654752f));
                    oh[(size_t)r * Ncols + c] = f2bf(gl);
                }
            }
}

// ---------------------------------------------------------------------------
// Flash attention, bf16 MFMA, z = layer (z==0 causal, z==1 anti-causal).
// R19: QBLK=128 (wave owns 32 q-rows, qf=0/1); m_ init 0 (shift-invariant
// online softmax; no NaN on fully-masked tiles). att[2] pipeline per qf.
// ---------------------------------------------------------------------------
__global__ __launch_bounds__(256) void attn_mfma(const u16* __restrict__ QKV,
    u16* __restrict__ AO0, u16* __restrict__ AO1)
{
    __shared__ u16 Ks[2][64 * 64];
    __shared__ u16 Vs[2][64 * 64];
    const int t = threadIdx.x, l = t & 63, w = t >> 6;
    const int lr = l & 15, lg = l >> 4;
    const int z = blockIdx.z;
    const int causal = (z == 0);
    const int bh = blockIdx.x;
    const int b = bh >> 3, h = bh & 7;
    const int qt = causal ? (7 - (int)blockIdx.y) : (int)blockIdx.y;  // long first
    const u16* base = QKV + ((size_t)z * 4096 + (size_t)b * NTOK) * 1536;
    u16* AO = z ? AO1 : AO0;
    const int q0 = qt * 128 + w * 32;     // wave's 32 q-rows

    // Q fragments: qf=0 rows q0..q0+15, qf=1 rows q0+16..q0+31
    s16x8 aq[2][2];
    #pragma unroll
    for (int qf = 0; qf < 2; qf++) {
        aq[qf][0] = *(const s16x8*)&base[(size_t)(q0 + qf * 16 + lr) * 1536 + h * 64 + lg * 8];
        aq[qf][1] = *(const s16x8*)&base[(size_t)(q0 + qf * 16 + lr) * 1536 + h * 64 + 32 + lg * 8];
    }

    f32x4 o[2][4];
    float m_[2] = {0.f, 0.f};            // finite init: shift-invariant, NaN-safe
    float l_[2] = {0.f, 0.f};
    #pragma unroll
    for (int qf = 0; qf < 2; qf++)
        #pragma unroll
        for (int f = 0; f < 4; f++) o[qf][f] = f32x4{0.f, 0.f, 0.f, 0.f};

    const int kt0 = causal ? 0 : 2 * qt;
    const int kt1 = causal ? (2 * qt + 1) : 15;

    auto stageK = [&](int kt) {
        #pragma unroll
        for (int i = 0; i < 2; i++) {
            const int j = w * 2 + i;
            const int r = j * 8 + (l >> 3);
            const int ck = (l & 7) ^ (r & 7);
            gll16(&base[(size_t)(kt * 64 + r) * 1536 + 512 + h * 64 + ck * 8],
                  &Ks[kt & 1][j * 512]);
        }
    };
    const int jv = t & 63;
    s16x8 va, vb;
    auto loadV = [&](int kt) {
        const u16* vr = &base[(size_t)(kt * 64 + jv) * 1536 + 1024 + h * 64 + w * 16];
        va = *(const s16x8*)&vr[0];
        vb = *(const s16x8*)&vr[8];
    };
    auto writeV = [&](int kt) {
        #pragma unroll
        for (int i = 0; i < 8; i++) {
            const int d = w * 16 + i;
            Vs[kt & 1][d * 64 + (((jv >> 3) ^ (d & 7)) << 3) + (jv & 7)] = (u16)va[i];
        }
        #pragma unroll
        for (int i = 0; i < 8; i++) {
            const int d = w * 16 + 8 + i;
            Vs[kt & 1][d * 64 + (((jv >> 3) ^ (d & 7)) << 3) + (jv & 7)] = (u16)vb[i];
        }
    };

    s16x8 pap[2][2];
    float psc[2][4] = {{1.f,1.f,1.f,1.f},{1.f,1.f,1.f,1.f}};
    int pneed[2] = {0, 0};

    auto QK = [&](int kt, int qf, f32x4* s) {
        #pragma unroll
        for (int f = 0; f < 4; f++) s[f] = f32x4{0.f, 0.f, 0.f, 0.f};
        #pragma unroll
        for (int kk = 0; kk < 2; kk++)
            #pragma unroll
            for (int f = 0; f < 4; f++) {
                const int row = f * 16 + lr;
                const int ch = kk * 4 + lg;
                s16x8 bk = *(const s16x8*)&Ks[kt & 1][row * 64 + ((ch ^ (row & 7)) << 3)];
                s[f] = __builtin_amdgcn_mfma_f32_16x16x32_bf16(bk, aq[qf][kk], s[f], 0, 0, 0);
            }
        const int needMask = causal ? (kt >= 2 * qt) : (kt <= 2 * qt + 1);
        if (needMask) {
            const int q = q0 + qf * 16 + lr;
            #pragma unroll
            for (int f = 0; f < 4; f++)
                #pragma unroll
                for (int r = 0; r < 4; r++) {
                    const int key = kt * 64 + f * 16 + lg * 4 + r;
                    if (causal ? (key > q) : (key < q)) s[f][r] = -INFINITY;
                }
        }
    };

    auto SM = [&](int qf, f32x4* s) {
        float rm = s[0][0];
        #pragma unroll
        for (int f = 0; f < 4; f++)
            #pragma unroll
            for (int r = 0; r < 4; r++) rm = fmaxf(rm, s[f][r]);
        rm = fmaxf(rm, __shfl_xor(rm, 16));
        rm = fmaxf(rm, __shfl_xor(rm, 32));
        pneed[qf] = !__all(rm <= m_[qf] + 8.f);       // defer-max (T13)
        const float mn = pneed[qf] ? fmaxf(m_[qf], rm) : m_[qf];
        const float sc = __expf(m_[qf] - mn);         // ==1 when deferred
        float ps = 0.f;
        #pragma unroll
        for (int f = 0; f < 4; f++)
            #pragma unroll
            for (int r = 0; r < 4; r++) {
                float p = __expf(s[f][r] - mn);
                s[f][r] = p;
                ps += p;
            }
        ps += __shfl_xor(ps, 16);
        ps += __shfl_xor(ps, 32);
        l_[qf] = l_[qf] * sc + ps;
        m_[qf] = mn;
        u32 P01[4], P23[4];
        #pragma unroll
        for (int f = 0; f < 4; f++) {
            P01[f] = cvtpk(s[f][0], s[f][1]);
            P23[f] = cvtpk(s[f][2], s[f][3]);
        }
        const int srcA = lr + ((lg & 1) << 5);
        const int srcB = srcA + 16;
        #pragma unroll
        for (int kk = 0; kk < 2; kk++) {
            const u32 a01_0 = (u32)__shfl((int)P01[2 * kk], srcA);
            const u32 a01_1 = (u32)__shfl((int)P01[2 * kk + 1], srcA);
            const u32 a23_0 = (u32)__shfl((int)P23[2 * kk], srcA);
            const u32 a23_1 = (u32)__shfl((int)P23[2 * kk + 1], srcA);
            const u32 b01_0 = (u32)__shfl((int)P01[2 * kk], srcB);
            const u32 b01_1 = (u32)__shfl((int)P01[2 * kk + 1], srcB);
            const u32 b23_0 = (u32)__shfl((int)P23[2 * kk], srcB);
            const u32 b23_1 = (u32)__shfl((int)P23[2 * kk + 1], srcB);
            i32x4 av;
            av[0] = (int)((lg & 2) ? a01_1 : a01_0);
            av[1] = (int)((lg & 2) ? a23_1 : a23_0);
            av[2] = (int)((lg & 2) ? b01_1 : b01_0);
            av[3] = (int)((lg & 2) ? b23_1 : b23_0);
            pap[qf][kk] = __builtin_bit_cast(s16x8, av);
        }
        if (pneed[qf]) {
            #pragma unroll
            for (int r = 0; r < 4; r++) psc[qf][r] = __shfl(sc, lg * 4 + r);
        }
    };

    auto PV = [&](int kt, int qf) {
        if (pneed[qf]) {
            #pragma unroll
            for (int r = 0; r < 4; r++)
                #pragma unroll
                for (int f = 0; f < 4; f++) o[qf][f][r] *= psc[qf][r];
        }
        #pragma unroll
        for (int kk = 0; kk < 2; kk++)
            #pragma unroll
            for (int f = 0; f < 4; f++) {
                const int row = f * 16 + lr;
                const int ch = kk * 4 + lg;
                s16x8 bv = *(const s16x8*)&Vs[kt & 1][row * 64 + ((ch ^ (row & 7)) << 3)];
                o[qf][f] = __builtin_amdgcn_mfma_f32_16x16x32_bf16(pap[qf][kk], bv, o[qf][f], 0, 0, 0);
            }
    };

    // ---- prologue ----
    stageK(kt0);
    stageK(kt0 + 1);      // kt1 >= kt0+1 always (>=2 k-tiles per q-tile)
    loadV(kt0);
    writeV(kt0);
    __syncthreads();
    {
        f32x4 s0[4];
        QK(kt0, 0, s0);
        SM(0, s0);
        QK(kt0, 1, s0);
        SM(1, s0);
    }
    __syncthreads();

    // ---- main loop: per iter { QK(t+1,qf) -> PV(t,qf) -> SM(qf) } x2 ----
    for (int kt = kt0; kt <= kt1; kt++) {
        if (kt + 2 <= kt1) stageK(kt + 2);
        if (kt + 1 <= kt1) loadV(kt + 1);
        f32x4 sn[4];
        __builtin_amdgcn_s_setprio(1);
        if (kt + 1 <= kt1) QK(kt + 1, 0, sn);
        PV(kt, 0);
        if (kt + 1 <= kt1) SM(0, sn);
        if (kt + 1 <= kt1) QK(kt + 1, 1, sn);
        PV(kt, 1);
        __builtin_amdgcn_s_setprio(0);
        if (kt + 1 <= kt1) {
            SM(1, sn);
            writeV(kt + 1);
        }
        __syncthreads();
    }

    // ---- epilogue: bf16 AO, head-slow merge ----
    #pragma unroll
    for (int qf = 0; qf < 2; qf++) {
        const float linv = 1.f / l_[qf];
        #pragma unroll
        for (int r = 0; r < 4; r++) {
            const float lv = __shfl(linv, lg * 4 + r);
            #pragma unroll
            for (int f = 0; f < 4; f++)
                AO[(size_t)(b * NTOK + q0 + qf * 16 + lg * 4 + r) * PL + h * 64 + f * 16 + lr] =
                    f2bf(o[qf][f][r] * lv);
        }
    }
}

// ---------------------------------------------------------------------------
// add+LN A: x(f32)+attn(bf16) -> LN -> single bf16 x1. z = layer.
// ---------------------------------------------------------------------------
__global__ __launch_bounds__(256) void add_ln_a(const float* __restrict__ X,
    const u16* __restrict__ A0, const u16* __restrict__ A1,
    const float* __restrict__ g0, const float* __restrict__ g1,
    const float* __restrict__ be0, const float* __restrict__ be1,
    u16* __restrict__ OB, const size_t oLS)
{
    const int z = blockIdx.z;
    const u16* A = z ? A1 : A0;
    const float* g = z ? g1 : g0;
    const float* be = z ? be1 : be0;
    u16* O = OB + (size_t)z * oLS;
    const int row = blockIdx.x * 4 + (threadIdx.x >> 6);
    const int lane = threadIdx.x & 63;
    const float* xr = X + (size_t)row * PL;
    const u16* ar = A + (size_t)row * PL;
    float v[8];
    float sum = 0.f;
    #pragma unroll
    for (int u = 0; u < 8; u++) { v[u] = xr[lane + u * 64] + bf2f(ar[lane + u * 64]); sum += v[u]; }
    #pragma unroll
    for (int o = 32; o > 0; o >>= 1) sum += __shfl_xor(sum, o);
    const float mu = sum * (1.f / 512.f);
    float s2 = 0.f;
    #pragma unroll
    for (int u = 0; u < 8; u++) { float d = v[u] - mu; s2 = fmaf(d, d, s2); }
    #pragma unroll
    for (int o = 32; o > 0; o >>= 1) s2 += __shfl_xor(s2, o);
    const float rstd = rsqrtf(s2 * (1.f / 512.f) + 1e-5f);
    #pragma unroll
    for (int u = 0; u < 8; u++) {
        const int c = lane + u * 64;
        O[(size_t)row * PL + c] = f2bf((v[u] - mu) * rstd * g[c] + be[c]);
    }
}

// ---------------------------------------------------------------------------
// add+LN B: x1(bf16) + ffo(bf16) -> LN -> sigmoid -> bf16 td. z = layer.
// ---------------------------------------------------------------------------
__global__ __launch_bounds__(256) void add_ln_b(
    const u16* __restrict__ X1B, const size_t xLS,
    const u16* __restrict__ FB, const size_t fLS,
    const float* __restrict__ g0, const float* __restrict__ g1,
    const float* __restrict__ be0, const float* __restrict__ be1,
    u16* __restrict__ TDB, const size_t tLS)
{
    const int z = blockIdx.z;
    const u16* X1 = X1B + (size_t)z * xLS;
    const u16* F = FB + (size_t)z * fLS;
    const float* g = z ? g1 : g0;
    const float* be = z ? be1 : be0;
    u16* TD = TDB + (size_t)z * tLS;
    const int row = blockIdx.x * 4 + (threadIdx.x >> 6);
    const int lane = threadIdx.x & 63;
    const size_t ro = (size_t)row * PL;
    float v[8];
    float sum = 0.f;
    #pragma unroll
    for (int u = 0; u < 8; u++) {
        const int c = lane + u * 64;
        v[u] = bf2f(X1[ro + c]) + bf2f(F[ro + c]);
        sum += v[u];
    }
    #pragma unroll
    for (int o = 32; o > 0; o >>= 1) sum += __shfl_xor(sum, o);
    const float mu = sum * (1.f / 512.f);
    float s2 = 0.f;
    #pragma unroll
    for (int u = 0; u < 8; u++) { float d = v[u] - mu; s2 = fmaf(d, d, s2); }
    #pragma unroll
    for (int o = 32; o > 0; o >>= 1) s2 += __shfl_xor(s2, o);
    const float rstd = rsqrtf(s2 * (1.f / 512.f) + 1e-5f);
    #pragma unroll
    for (int u = 0; u < 8; u++) {
        const int c = lane + u * 64;
        float y = (v[u] - mu) * rstd * g[c] + be[c];
        TD[ro + c] = f2bf(1.f / (1.f + expf(-y)));
    }
}

// ---------------------------------------------------------------------------
// sim: per batch, C[i][j] = dot(td1[i,:], td2[j,:]) / 512  (plain bf16 MFMA)
// 64x128 tiles -> 512 blocks. gll-staged, BK=64, dbuf.
// ---------------------------------------------------------------------------
__global__ __launch_bounds__(256) void sim_mfma(const u16* __restrict__ TD1,
    const u16* __restrict__ TD2, float* __restrict__ Out)
{
    __shared__ u16 Ah[2][64 * 64], Bh[2][128 * 64];
    const int t = threadIdx.x, l = t & 63, w = t >> 6;
    const int lr = l & 15, lg = l >> 4;
    const int wm = w >> 1, wn = w & 1;
    const int bz = blockIdx.z;
    const u16* A = TD1 + (size_t)bz * NTOK * PL;
    const u16* B = TD2 + (size_t)bz * NTOK * PL;
    const int m0 = blockIdx.x * 64, n0 = blockIdx.y * 128;

    f32x4 acc[2][4];
    #pragma unroll
    for (int i = 0; i < 2; i++)
        #pragma unroll
        for (int j = 0; j < 4; j++) acc[i][j] = f32x4{0.f, 0.f, 0.f, 0.f};

    auto stage = [&](int bufi, int k0) {
        #pragma unroll
        for (int i = 0; i < 2; i++) {
            const int j = w * 2 + i;
            const int r = j * 8 + (l >> 3);
            const int ck = (l & 7) ^ (r & 7);
            gll16(&A[(size_t)(m0 + r) * 512 + k0 + ck * 8], &Ah[bufi][j * 512]);
        }
        #pragma unroll
        for (int i = 0; i < 4; i++) {
            const int j = w * 4 + i;
            const int r = j * 8 + (l >> 3);
            const int ck = (l & 7) ^ (r & 7);
            gll16(&B[(size_t)(n0 + r) * 512 + k0 + ck * 8], &Bh[bufi][j * 512]);
        }
    };

    stage(0, 0);
    __syncthreads();
    int buf = 0;
    for (int kt = 0; kt < 8; kt++) {
        if (kt < 7) stage(buf ^ 1, (kt + 1) * 64);
        #pragma unroll
        for (int kk = 0; kk < 2; kk++) {
            const int ch = kk * 4 + lg;
            s16x8 af[2], bf[4];
            #pragma unroll
            for (int fm = 0; fm < 2; fm++) {
                const int r = wm * 32 + fm * 16 + lr;
                af[fm] = *(const s16x8*)&Ah[buf][r * 64 + ((ch ^ (r & 7)) << 3)];
            }
            #pragma unroll
            for (int fn = 0; fn < 4; fn++) {
                const int r = wn * 64 + fn * 16 + lr;
                bf[fn] = *(const s16x8*)&Bh[buf][r * 64 + ((ch ^ (r & 7)) << 3)];
            }
            #pragma unroll
            for (int fm = 0; fm < 2; fm++)
                #pragma unroll
                for (int fn = 0; fn < 4; fn++)
                    acc[fm][fn] = __builtin_amdgcn_mfma_f32_16x16x32_bf16(af[fm], bf[fn], acc[fm][fn], 0, 0, 0);
        }
        __syncthreads();
        buf ^= 1;
    }
    #pragma unroll
    for (int fm = 0; fm < 2; fm++)
        #pragma unroll
        for (int fn = 0; fn < 4; fn++)
            #pragma unroll
            for (int rg = 0; rg < 4; rg++) {
                const int r = m0 + wm * 32 + fm * 16 + lg * 4 + rg;
                const int c = n0 + wn * 64 + fn * 16 + lr;
                Out[((size_t)(bz * NTOK + r)) * NTOK + c] = acc[fm][fn][rg] * (1.f / 512.f);
            }
}

// ---------------------------------------------------------------------------
extern "C" void kernel_launch(void* const* d_in, const int* in_sizes, int n_in,
                              void* d_out, int out_size, void* d_ws, size_t ws_size,
                              hipStream_t stream)
{
    const float* x = (const float*)d_in[0];
    const float* wqkv[2] = {(const float*)d_in[1],  (const float*)d_in[11]};
    const float* bqkv[2] = {(const float*)d_in[2],  (const float*)d_in[12]};
    const float* ga[2]   = {(const float*)d_in[3],  (const float*)d_in[13]};
    const float* bea[2]  = {(const float*)d_in[4],  (const float*)d_in[14]};
    const float* w1[2]   = {(const float*)d_in[5],  (const float*)d_in[15]};
    const float* b1[2]   = {(const float*)d_in[6],  (const float*)d_in[16]};
    const float* w2[2]   = {(const float*)d_in[7],  (const float*)d_in[17]};
    const float* b2[2]   = {(const float*)d_in[8],  (const float*)d_in[18]};
    const float* gb[2]   = {(const float*)d_in[9],  (const float*)d_in[19]};
    const float* beb[2]  = {(const float*)d_in[10], (const float*)d_in[20]};

    // -------- workspace map (KB offsets; lifetimes verified stage-by-stage) --
    char* wsb = (char*)d_ws;
    char* ob  = (char*)d_out;
    #define WSK(kb) ((char*)wsb + ((size_t)(kb) << 10))
    #define OBK(kb) ((char*)ob  + ((size_t)(kb) << 10))
    // ws [0,4M):  xhi (S0-S2);  ws [0,8M): x1 z0/z1 (S4-S7)
    u16* xhi = (u16*)WSK(0);
    u16* x1  = (u16*)WSK(0);          // + z*2097152 elems
    // ws [8,11M): wqh (S1-S2) -> td (S7-): td1 [8,12M), td2 [12,16M)
    u16* wqh = (u16*)WSK(8192);       // + z*786432 elems
    u16* td1 = (u16*)WSK(8192);
    u16* td2 = (u16*)WSK(12288);
    // ws [11,13M): w1h [11,12M), w2h [12,13M) (S1-S6; dead before td writes)
    u16* w1h = (u16*)WSK(11264);      // + z*262144 elems
    u16* w2h = (u16*)WSK(12288);      // + z*262144 elems
    // ws [13,37M): qkvB (S2-S3)
    u16* qkvB = (u16*)WSK(13312);     // [z][4096][1536]
    // ws [24,32M): ffo single bf16 (S6-S7; qkvB dead)
    u16* ffo = (u16*)WSK(24576);      // + z*2097152 elems
    // d_out: AO bf16 (S3-S4) [0,8M); h bf16 (S5-S6) [8,16M); final out (S8)
    u16* AO0 = (u16*)OBK(0);
    u16* AO1 = (u16*)OBK(4096);
    u16* hB  = (u16*)OBK(8192);       // + z*2097152 elems
    float* out = (float*)d_out;

    // S0+S1: merged prep (x convert + 3 weight transposes)
    prep<<<4608, 256, 0, stream>>>(x, xhi,
        wqkv[0], wqkv[1], wqh, w1[0], w1[1], w1h, w2[0], w2[1], w2h);
    // S2: qkv gemm — BM=128 (768 blocks), 1-term, permuted-B
    gemm_mfma<128, 0><<<dim3(32, 12, 2), 256, 0, stream>>>(
        xhi, 0, wqh, 786432, bqkv[0], bqkv[1], 1536,
        qkvB, qkvB);
    // S3: attention (z=0 causal, z=1 anti-causal), QBLK=128, bf16 AO
    attn_mfma<<<dim3(32, 8, 2), 256, 0, stream>>>(qkvB, AO0, AO1);
    // S4: add + LN -> x1 single bf16
    add_ln_a<<<dim3(1024, 1, 2), 256, 0, stream>>>(x, AO0, AO1,
        ga[0], ga[1], bea[0], bea[1], x1, 2097152);
    // S5: ff1 (gelu) -> h bf16 (d_out [8,16M)), BM=64
    gemm_mfma<64, 1><<<dim3(64, 4, 2), 256, 0, stream>>>(
        x1, 2097152, w1h, 262144, b1[0], b1[1], 512,
        hB, hB + 2097152);
    // S6: ff2 -> ffo bf16 (ws), BM=64
    gemm_mfma<64, 2><<<dim3(64, 4, 2), 256, 0, stream>>>(
        hB, 2097152, w2h, 262144, b2[0], b2[1], 512,
        ffo, ffo + 2097152);
    // S7: add + LN + sigmoid -> td
    add_ln_b<<<dim3(1024, 1, 2), 256, 0, stream>>>(
        x1, 2097152, ffo, 2097152,
        gb[0], gb[1], beb[0], beb[1], td1, 2097152);
    // S8: sim (64x128 tiles, 512 blocks)
    sim_mfma<<<dim3(16, 8, 4), 256, 0, stream>>>(td1, td2, out);
}

// Round 20
// 125.678 us; speedup vs baseline: 1.0878x; 1.0878x over previous
//
#include <hip/hip_runtime.h>
#include <math.h>

// ---------------------------------------------------------------------------
// bf16-MFMA implementation, both layers merged (z=2), global_load_lds staging.
//  - all GEMMs 1-term plain bf16; qkv BM=128, FF BM=64 (R17-proven optimum)
//  - attention QBLK=64 (R17-proven; R18/R19's QBLK=128 regressed: block count
//    beats per-block amortization for latency-bound kernels)
//  - qkv linear [z][4096][1536] output via permuted weight rows (R10)
//  - attention core: R12 att[2] pipeline (swapped QK^T, in-reg P, defer-max,
//    setprio)
// ---------------------------------------------------------------------------

typedef float f32x4 __attribute__((ext_vector_type(4)));
typedef short s16x8 __attribute__((ext_vector_type(8)));
typedef int   i32x4 __attribute__((ext_vector_type(4)));
typedef unsigned short u16;
typedef unsigned int u32;

#define NTOK 1024
#define PL 512
#define QSCALE 0.04419417382415922f  // 1/sqrt(512)

__device__ inline u16 f2bf(float f) {
    unsigned u = __builtin_bit_cast(unsigned, f);
    unsigned r = u + 0x7fffu + ((u >> 16) & 1u);   // RNE
    return (u16)(r >> 16);
}
__device__ inline float bf2f(u16 h) {
    unsigned u = ((unsigned)h) << 16;
    return __builtin_bit_cast(float, u);
}
__device__ inline u32 cvtpk(float a, float b) {   // lo=a, hi=b (RNE)
    u32 r;
    asm("v_cvt_pk_bf16_f32 %0, %1, %2" : "=v"(r) : "v"(a), "v"(b));
    return r;
}

__device__ inline void gll16(const void* g, void* l) {
    __builtin_amdgcn_global_load_lds(
        (const __attribute__((address_space(1))) u32*)g,
        (__attribute__((address_space(3))) u32*)l, 16, 0, 0);
}

// ---------------------------------------------------------------------------
// Merged prep: blockIdx ranges -> {x->bf16, wqkv^T, w1^T, w2^T}
// ---------------------------------------------------------------------------
__global__ __launch_bounds__(256) void prep(const float* __restrict__ X,
    u16* __restrict__ xhi,
    const float* __restrict__ Wq0, const float* __restrict__ Wq1, u16* __restrict__ wqh,
    const float* __restrict__ W10, const float* __restrict__ W11, u16* __restrict__ w1h,
    const float* __restrict__ W20, const float* __restrict__ W21, u16* __restrict__ w2h)
{
    const int bid = blockIdx.x;
    if (bid < 2048) {
        const int i = (bid * 256 + threadIdx.x) * 4;
        float4 v = *(const float4*)&X[i];
        xhi[i + 0] = f2bf(v.x); xhi[i + 1] = f2bf(v.y);
        xhi[i + 2] = f2bf(v.z); xhi[i + 3] = f2bf(v.w);
        return;
    }
    const float* W;
    u16* Whi;
    int N, kx, ny;
    if (bid < 3584) {
        const int idx = bid - 2048;
        const int z = idx / 768, rem = idx % 768;
        kx = rem % 16; ny = rem / 16;
        W = z ? Wq1 : Wq0; Whi = wqh + (size_t)z * 786432; N = 1536;
    } else if (bid < 4096) {
        const int idx = bid - 3584;
        const int z = idx / 256, rem = idx % 256;
        kx = rem % 16; ny = rem / 16;
        W = z ? W11 : W10; Whi = w1h + (size_t)z * 262144; N = 512;
    } else {
        const int idx = bid - 4096;
        const int z = idx / 256, rem = idx % 256;
        kx = rem % 16; ny = rem / 16;
        W = z ? W21 : W20; Whi = w2h + (size_t)z * 262144; N = 512;
    }
    __shared__ float T[32][36];
    const int k0 = kx * 32, n0 = ny * 32;
    const int tr = threadIdx.x >> 3, tc = (threadIdx.x & 7) * 4;
    *(float4*)&T[tr][tc] = *(const float4*)&W[(size_t)(k0 + tr) * N + n0 + tc];
    __syncthreads();
    const size_t o = (size_t)(n0 + tr) * 512 + k0 + tc;
    #pragma unroll
    for (int j = 0; j < 4; j++) Whi[o + j] = f2bf(T[tc + j][tr]);
}

// π: permuted col j -> original col (head-fast split c2 = dd*8+h)
__device__ inline int qkv_perm(int j) {
    return (j >> 9) * 512 + ((j & 63) << 3) + ((j >> 6) & 7);
}

// ---------------------------------------------------------------------------
// 1-term bf16 MFMA GEMM, z = layer. A[4096][512] x Bt[N][512].
// EPI: 0 = qkv (B rows permuted, linear output, Q scaled),
//      1 = gelu -> bf16, 2 = plain bf16.
// BK=32; dbuf gll staging. Wave (wm,wn): rows [wm*BM/2,+BM/2) x cols [wn*64,+64).
// ---------------------------------------------------------------------------
template<int BM, int EPI>
__global__ __launch_bounds__(256) void gemm_mfma(
    const u16* __restrict__ AB, const size_t aLS,
    const u16* __restrict__ BB, const size_t bLS,
    const float* __restrict__ bias0, const float* __restrict__ bias1, const int Ncols,
    u16* __restrict__ oh0, u16* __restrict__ oh1)
{
    constexpr int FM = BM / 32;          // fragments per wave in M
    constexpr int WMS = BM / 2;          // wave M-stride
    __shared__ u16 Ah[2][BM * 32], Bh[2][128 * 32];
    const int z = blockIdx.z;
    const u16* A = AB + (size_t)z * aLS;
    const u16* B = BB + (size_t)z * bLS;
    const float* bias = z ? bias1 : bias0;
    u16* oh = z ? oh1 : oh0;

    const int t = threadIdx.x, l = t & 63, w = t >> 6;
    const int lr = l & 15, lg = l >> 4;
    const int wm = w >> 1, wn = w & 1;
    const int m0 = blockIdx.x * BM, n0 = blockIdx.y * 128;
    const int srow = l >> 2, sch = l & 3;    // staging lane coords (16 rows/KB)

    f32x4 acc[FM][4];
    #pragma unroll
    for (int i = 0; i < FM; i++)
        #pragma unroll
        for (int j = 0; j < 4; j++) acc[i][j] = f32x4{0.f, 0.f, 0.f, 0.f};

    auto stage = [&](int bufi, int k0) {
        for (int j = w; j < BM / 16; j += 4) {
            const int r = j * 16 + srow;
            const int ck = sch ^ ((r >> 1) & 3);
            gll16(&A[(size_t)(m0 + r) * 512 + k0 + ck * 8], &Ah[bufi][j * 512]);
        }
        for (int j = w; j < 8; j += 4) {
            const int r = j * 16 + srow;
            const int ck = sch ^ ((r >> 1) & 3);
            const int brow = (EPI == 0) ? qkv_perm(n0 + r) : (n0 + r);
            gll16(&B[(size_t)brow * 512 + k0 + ck * 8], &Bh[bufi][j * 512]);
        }
    };

    stage(0, 0);
    __syncthreads();
    int buf = 0;
    for (int kt = 0; kt < 16; kt++) {
        if (kt < 15) stage(buf ^ 1, (kt + 1) * 32);

        s16x8 ah[FM];
        #pragma unroll
        for (int fm = 0; fm < FM; fm++) {
            const int r = wm * WMS + fm * 16 + lr;
            ah[fm] = *(const s16x8*)&Ah[buf][r * 32 + ((lg ^ ((r >> 1) & 3)) << 3)];
        }
        #pragma unroll
        for (int fn = 0; fn < 4; fn++) {
            const int r = wn * 64 + fn * 16 + lr;
            s16x8 bh = *(const s16x8*)&Bh[buf][r * 32 + ((lg ^ ((r >> 1) & 3)) << 3)];
            #pragma unroll
            for (int fm = 0; fm < FM; fm++)
                acc[fm][fn] = __builtin_amdgcn_mfma_f32_16x16x32_bf16(ah[fm], bh, acc[fm][fn], 0, 0, 0);
        }
        __syncthreads();   // waves done with buf; stage(buf^1) drained
        buf ^= 1;
    }
    // epilogue: every wave writes its own (wm,wn) sub-tile
    #pragma unroll
    for (int fm = 0; fm < FM; fm++)
        #pragma unroll
        for (int fn = 0; fn < 4; fn++)
            #pragma unroll
            for (int rg = 0; rg < 4; rg++) {
                const int r = m0 + wm * WMS + fm * 16 + lg * 4 + rg;
                const int c = n0 + wn * 64 + fn * 16 + lr;
                if constexpr (EPI == 0) {
                    float v = acc[fm][fn][rg] + bias[qkv_perm(c)];
                    if (c < 512) v *= QSCALE;   // Q third (uniform per block)
                    oh[((size_t)z * 4096 + r) * Ncols + c] = f2bf(v);
                } else {
                    float gl = acc[fm][fn][rg] + bias[c];
                    if constexpr (EPI == 1)
                        gl = 0.5f * gl * (1.f + erff(gl * 0.70710678118654752f));
                    oh[(size_t)r * Ncols + c] = f2bf(gl);
                }
            }
}

// ---------------------------------------------------------------------------
// Flash attention, bf16 MFMA, z = layer (z==0 causal, z==1 anti-causal).
// R12 structure; AO output bf16. QBLK=64, grid (32,16,2).
// ---------------------------------------------------------------------------
__global__ __launch_bounds__(256) void attn_mfma(const u16* __restrict__ QKV,
    u16* __restrict__ AO0, u16* __restrict__ AO1)
{
    __shared__ u16 Ks[2][64 * 64];
    __shared__ u16 Vs[2][64 * 64];
    const int t = threadIdx.x, l = t & 63, w = t >> 6;
    const int lr = l & 15, lg = l >> 4;
    const int z = blockIdx.z;
    const int causal = (z == 0);
    const int bh = blockIdx.x;
    const int b = bh >> 3, h = bh & 7;
    const int qt = causal ? (15 - (int)blockIdx.y) : (int)blockIdx.y;  // long jobs first
    const u16* base = QKV + ((size_t)z * 4096 + (size_t)b * NTOK) * 1536;
    u16* AO = z ? AO1 : AO0;
    const int q0 = qt * 64 + w * 16;

    s16x8 aq[2];
    aq[0] = *(const s16x8*)&base[(size_t)(q0 + lr) * 1536 + h * 64 + lg * 8];
    aq[1] = *(const s16x8*)&base[(size_t)(q0 + lr) * 1536 + h * 64 + 32 + lg * 8];

    f32x4 o[4];
    float m_ = -INFINITY, l_ = 0.f;
    #pragma unroll
    for (int f = 0; f < 4; f++) o[f] = f32x4{0.f, 0.f, 0.f, 0.f};

    const int kt0 = causal ? 0 : qt, kt1 = causal ? qt : 15;

    auto stageK = [&](int kt) {
        #pragma unroll
        for (int i = 0; i < 2; i++) {
            const int j = w * 2 + i;
            const int r = j * 8 + (l >> 3);
            const int ck = (l & 7) ^ (r & 7);
            gll16(&base[(size_t)(kt * 64 + r) * 1536 + 512 + h * 64 + ck * 8],
                  &Ks[kt & 1][j * 512]);
        }
    };
    const int jv = t & 63;
    s16x8 va, vb;
    auto loadV = [&](int kt) {
        const u16* vr = &base[(size_t)(kt * 64 + jv) * 1536 + 1024 + h * 64 + w * 16];
        va = *(const s16x8*)&vr[0];
        vb = *(const s16x8*)&vr[8];
    };
    auto writeV = [&](int kt) {
        #pragma unroll
        for (int i = 0; i < 8; i++) {
            const int d = w * 16 + i;
            Vs[kt & 1][d * 64 + (((jv >> 3) ^ (d & 7)) << 3) + (jv & 7)] = (u16)va[i];
        }
        #pragma unroll
        for (int i = 0; i < 8; i++) {
            const int d = w * 16 + 8 + i;
            Vs[kt & 1][d * 64 + (((jv >> 3) ^ (d & 7)) << 3) + (jv & 7)] = (u16)vb[i];
        }
    };

    s16x8 pap[2];
    float psc[4] = {1.f, 1.f, 1.f, 1.f};
    int pneed = 1;

    auto QK = [&](int kt, f32x4* s) {
        #pragma unroll
        for (int f = 0; f < 4; f++) s[f] = f32x4{0.f, 0.f, 0.f, 0.f};
        #pragma unroll
        for (int kk = 0; kk < 2; kk++)
            #pragma unroll
            for (int f = 0; f < 4; f++) {
                const int row = f * 16 + lr;
                const int ch = kk * 4 + lg;
                s16x8 bk = *(const s16x8*)&Ks[kt & 1][row * 64 + ((ch ^ (row & 7)) << 3)];
                s[f] = __builtin_amdgcn_mfma_f32_16x16x32_bf16(bk, aq[kk], s[f], 0, 0, 0);
            }
        if (kt == qt) {
            const int q = q0 + lr;
            #pragma unroll
            for (int f = 0; f < 4; f++)
                #pragma unroll
                for (int r = 0; r < 4; r++) {
                    const int key = kt * 64 + f * 16 + lg * 4 + r;
                    if (causal ? (key > q) : (key < q)) s[f][r] = -INFINITY;
                }
        }
    };

    auto SM = [&](f32x4* s) {
        float rm = s[0][0];
        #pragma unroll
        for (int f = 0; f < 4; f++)
            #pragma unroll
            for (int r = 0; r < 4; r++) rm = fmaxf(rm, s[f][r]);
        rm = fmaxf(rm, __shfl_xor(rm, 16));
        rm = fmaxf(rm, __shfl_xor(rm, 32));
        pneed = !__all(rm <= m_ + 8.f);          // defer-max (T13)
        const float mn = pneed ? fmaxf(m_, rm) : m_;
        const float sc = __expf(m_ - mn);        // ==1 when deferred
        float ps = 0.f;
        #pragma unroll
        for (int f = 0; f < 4; f++)
            #pragma unroll
            for (int r = 0; r < 4; r++) {
                float p = __expf(s[f][r] - mn);
                s[f][r] = p;
                ps += p;
            }
        ps += __shfl_xor(ps, 16);
        ps += __shfl_xor(ps, 32);
        l_ = l_ * sc + ps;
        m_ = mn;
        u32 P01[4], P23[4];
        #pragma unroll
        for (int f = 0; f < 4; f++) {
            P01[f] = cvtpk(s[f][0], s[f][1]);
            P23[f] = cvtpk(s[f][2], s[f][3]);
        }
        const int srcA = lr + ((lg & 1) << 5);
        const int srcB = srcA + 16;
        #pragma unroll
        for (int kk = 0; kk < 2; kk++) {
            const u32 a01_0 = (u32)__shfl((int)P01[2 * kk], srcA);
            const u32 a01_1 = (u32)__shfl((int)P01[2 * kk + 1], srcA);
            const u32 a23_0 = (u32)__shfl((int)P23[2 * kk], srcA);
            const u32 a23_1 = (u32)__shfl((int)P23[2 * kk + 1], srcA);
            const u32 b01_0 = (u32)__shfl((int)P01[2 * kk], srcB);
            const u32 b01_1 = (u32)__shfl((int)P01[2 * kk + 1], srcB);
            const u32 b23_0 = (u32)__shfl((int)P23[2 * kk], srcB);
            const u32 b23_1 = (u32)__shfl((int)P23[2 * kk + 1], srcB);
            i32x4 av;
            av[0] = (int)((lg & 2) ? a01_1 : a01_0);
            av[1] = (int)((lg & 2) ? a23_1 : a23_0);
            av[2] = (int)((lg & 2) ? b01_1 : b01_0);
            av[3] = (int)((lg & 2) ? b23_1 : b23_0);
            pap[kk] = __builtin_bit_cast(s16x8, av);
        }
        if (pneed) {
            #pragma unroll
            for (int r = 0; r < 4; r++) psc[r] = __shfl(sc, lg * 4 + r);
        }
    };

    auto PV = [&](int kt) {
        if (pneed) {
            #pragma unroll
            for (int r = 0; r < 4; r++)
                #pragma unroll
                for (int f = 0; f < 4; f++) o[f][r] *= psc[r];
        }
        #pragma unroll
        for (int kk = 0; kk < 2; kk++)
            #pragma unroll
            for (int f = 0; f < 4; f++) {
                const int row = f * 16 + lr;
                const int ch = kk * 4 + lg;
                s16x8 bv = *(const s16x8*)&Vs[kt & 1][row * 64 + ((ch ^ (row & 7)) << 3)];
                o[f] = __builtin_amdgcn_mfma_f32_16x16x32_bf16(pap[kk], bv, o[f], 0, 0, 0);
            }
    };

    // ---- prologue ----
    stageK(kt0);
    if (kt0 < kt1) stageK(kt0 + 1);
    loadV(kt0);
    writeV(kt0);
    __syncthreads();
    {
        f32x4 s0[4];
        QK(kt0, s0);
        SM(s0);
    }
    __syncthreads();

    // ---- main loop: QK(t+1) -> PV(t) -> SM(t+1) ----
    for (int kt = kt0; kt <= kt1; kt++) {
        if (kt + 2 <= kt1) stageK(kt + 2);
        if (kt + 1 <= kt1) loadV(kt + 1);
        f32x4 sn[4];
        __builtin_amdgcn_s_setprio(1);
        if (kt + 1 <= kt1) QK(kt + 1, sn);
        PV(kt);
        __builtin_amdgcn_s_setprio(0);
        if (kt + 1 <= kt1) {
            SM(sn);
            writeV(kt + 1);
        }
        __syncthreads();
    }

    // ---- epilogue: bf16 AO, head-slow merge ----
    const float linv = 1.f / l_;
    #pragma unroll
    for (int r = 0; r < 4; r++) {
        const float lv = __shfl(linv, lg * 4 + r);
        #pragma unroll
        for (int f = 0; f < 4; f++)
            AO[(size_t)(b * NTOK + q0 + lg * 4 + r) * PL + h * 64 + f * 16 + lr] =
                f2bf(o[f][r] * lv);
    }
}

// ---------------------------------------------------------------------------
// add+LN A: x(f32)+attn(bf16) -> LN -> single bf16 x1. z = layer.
// ---------------------------------------------------------------------------
__global__ __launch_bounds__(256) void add_ln_a(const float* __restrict__ X,
    const u16* __restrict__ A0, const u16* __restrict__ A1,
    const float* __restrict__ g0, const float* __restrict__ g1,
    const float* __restrict__ be0, const float* __restrict__ be1,
    u16* __restrict__ OB, const size_t oLS)
{
    const int z = blockIdx.z;
    const u16* A = z ? A1 : A0;
    const float* g = z ? g1 : g0;
    const float* be = z ? be1 : be0;
    u16* O = OB + (size_t)z * oLS;
    const int row = blockIdx.x * 4 + (threadIdx.x >> 6);
    const int lane = threadIdx.x & 63;
    const float* xr = X + (size_t)row * PL;
    const u16* ar = A + (size_t)row * PL;
    float v[8];
    float sum = 0.f;
    #pragma unroll
    for (int u = 0; u < 8; u++) { v[u] = xr[lane + u * 64] + bf2f(ar[lane + u * 64]); sum += v[u]; }
    #pragma unroll
    for (int o = 32; o > 0; o >>= 1) sum += __shfl_xor(sum, o);
    const float mu = sum * (1.f / 512.f);
    float s2 = 0.f;
    #pragma unroll
    for (int u = 0; u < 8; u++) { float d = v[u] - mu; s2 = fmaf(d, d, s2); }
    #pragma unroll
    for (int o = 32; o > 0; o >>= 1) s2 += __shfl_xor(s2, o);
    const float rstd = rsqrtf(s2 * (1.f / 512.f) + 1e-5f);
    #pragma unroll
    for (int u = 0; u < 8; u++) {
        const int c = lane + u * 64;
        O[(size_t)row * PL + c] = f2bf((v[u] - mu) * rstd * g[c] + be[c]);
    }
}

// ---------------------------------------------------------------------------
// add+LN B: x1(bf16) + ffo(bf16) -> LN -> sigmoid -> bf16 td. z = layer.
// ---------------------------------------------------------------------------
__global__ __launch_bounds__(256) void add_ln_b(
    const u16* __restrict__ X1B, const size_t xLS,
    const u16* __restrict__ FB, const size_t fLS,
    const float* __restrict__ g0, const float* __restrict__ g1,
    const float* __restrict__ be0, const float* __restrict__ be1,
    u16* __restrict__ TDB, const size_t tLS)
{
    const int z = blockIdx.z;
    const u16* X1 = X1B + (size_t)z * xLS;
    const u16* F = FB + (size_t)z * fLS;
    const float* g = z ? g1 : g0;
    const float* be = z ? be1 : be0;
    u16* TD = TDB + (size_t)z * tLS;
    const int row = blockIdx.x * 4 + (threadIdx.x >> 6);
    const int lane = threadIdx.x & 63;
    const size_t ro = (size_t)row * PL;
    float v[8];
    float sum = 0.f;
    #pragma unroll
    for (int u = 0; u < 8; u++) {
        const int c = lane + u * 64;
        v[u] = bf2f(X1[ro + c]) + bf2f(F[ro + c]);
        sum += v[u];
    }
    #pragma unroll
    for (int o = 32; o > 0; o >>= 1) sum += __shfl_xor(sum, o);
    const float mu = sum * (1.f / 512.f);
    float s2 = 0.f;
    #pragma unroll
    for (int u = 0; u < 8; u++) { float d = v[u] - mu; s2 = fmaf(d, d, s2); }
    #pragma unroll
    for (int o = 32; o > 0; o >>= 1) s2 += __shfl_xor(s2, o);
    const float rstd = rsqrtf(s2 * (1.f / 512.f) + 1e-5f);
    #pragma unroll
    for (int u = 0; u < 8; u++) {
        const int c = lane + u * 64;
        float y = (v[u] - mu) * rstd * g[c] + be[c];
        TD[ro + c] = f2bf(1.f / (1.f + expf(-y)));
    }
}

// ---------------------------------------------------------------------------
// sim: per batch, C[i][j] = dot(td1[i,:], td2[j,:]) / 512  (plain bf16 MFMA)
// 64x128 tiles -> 512 blocks. gll-staged, BK=64, dbuf.
// ---------------------------------------------------------------------------
__global__ __launch_bounds__(256) void sim_mfma(const u16* __restrict__ TD1,
    const u16* __restrict__ TD2, float* __restrict__ Out)
{
    __shared__ u16 Ah[2][64 * 64], Bh[2][128 * 64];
    const int t = threadIdx.x, l = t & 63, w = t >> 6;
    const int lr = l & 15, lg = l >> 4;
    const int wm = w >> 1, wn = w & 1;
    const int bz = blockIdx.z;
    const u16* A = TD1 + (size_t)bz * NTOK * PL;
    const u16* B = TD2 + (size_t)bz * NTOK * PL;
    const int m0 = blockIdx.x * 64, n0 = blockIdx.y * 128;

    f32x4 acc[2][4];
    #pragma unroll
    for (int i = 0; i < 2; i++)
        #pragma unroll
        for (int j = 0; j < 4; j++) acc[i][j] = f32x4{0.f, 0.f, 0.f, 0.f};

    auto stage = [&](int bufi, int k0) {
        #pragma unroll
        for (int i = 0; i < 2; i++) {
            const int j = w * 2 + i;
            const int r = j * 8 + (l >> 3);
            const int ck = (l & 7) ^ (r & 7);
            gll16(&A[(size_t)(m0 + r) * 512 + k0 + ck * 8], &Ah[bufi][j * 512]);
        }
        #pragma unroll
        for (int i = 0; i < 4; i++) {
            const int j = w * 4 + i;
            const int r = j * 8 + (l >> 3);
            const int ck = (l & 7) ^ (r & 7);
            gll16(&B[(size_t)(n0 + r) * 512 + k0 + ck * 8], &Bh[bufi][j * 512]);
        }
    };

    stage(0, 0);
    __syncthreads();
    int buf = 0;
    for (int kt = 0; kt < 8; kt++) {
        if (kt < 7) stage(buf ^ 1, (kt + 1) * 64);
        #pragma unroll
        for (int kk = 0; kk < 2; kk++) {
            const int ch = kk * 4 + lg;
            s16x8 af[2], bf[4];
            #pragma unroll
            for (int fm = 0; fm < 2; fm++) {
                const int r = wm * 32 + fm * 16 + lr;
                af[fm] = *(const s16x8*)&Ah[buf][r * 64 + ((ch ^ (r & 7)) << 3)];
            }
            #pragma unroll
            for (int fn = 0; fn < 4; fn++) {
                const int r = wn * 64 + fn * 16 + lr;
                bf[fn] = *(const s16x8*)&Bh[buf][r * 64 + ((ch ^ (r & 7)) << 3)];
            }
            #pragma unroll
            for (int fm = 0; fm < 2; fm++)
                #pragma unroll
                for (int fn = 0; fn < 4; fn++)
                    acc[fm][fn] = __builtin_amdgcn_mfma_f32_16x16x32_bf16(af[fm], bf[fn], acc[fm][fn], 0, 0, 0);
        }
        __syncthreads();
        buf ^= 1;
    }
    #pragma unroll
    for (int fm = 0; fm < 2; fm++)
        #pragma unroll
        for (int fn = 0; fn < 4; fn++)
            #pragma unroll
            for (int rg = 0; rg < 4; rg++) {
                const int r = m0 + wm * 32 + fm * 16 + lg * 4 + rg;
                const int c = n0 + wn * 64 + fn * 16 + lr;
                Out[((size_t)(bz * NTOK + r)) * NTOK + c] = acc[fm][fn][rg] * (1.f / 512.f);
            }
}

// ---------------------------------------------------------------------------
extern "C" void kernel_launch(void* const* d_in, const int* in_sizes, int n_in,
                              void* d_out, int out_size, void* d_ws, size_t ws_size,
                              hipStream_t stream)
{
    const float* x = (const float*)d_in[0];
    const float* wqkv[2] = {(const float*)d_in[1],  (const float*)d_in[11]};
    const float* bqkv[2] = {(const float*)d_in[2],  (const float*)d_in[12]};
    const float* ga[2]   = {(const float*)d_in[3],  (const float*)d_in[13]};
    const float* bea[2]  = {(const float*)d_in[4],  (const float*)d_in[14]};
    const float* w1[2]   = {(const float*)d_in[5],  (const float*)d_in[15]};
    const float* b1[2]   = {(const float*)d_in[6],  (const float*)d_in[16]};
    const float* w2[2]   = {(const float*)d_in[7],  (const float*)d_in[17]};
    const float* b2[2]   = {(const float*)d_in[8],  (const float*)d_in[18]};
    const float* gb[2]   = {(const float*)d_in[9],  (const float*)d_in[19]};
    const float* beb[2]  = {(const float*)d_in[10], (const float*)d_in[20]};

    // -------- workspace map (KB offsets; lifetimes verified stage-by-stage) --
    char* wsb = (char*)d_ws;
    char* ob  = (char*)d_out;
    #define WSK(kb) ((char*)wsb + ((size_t)(kb) << 10))
    #define OBK(kb) ((char*)ob  + ((size_t)(kb) << 10))
    // ws [0,4M):  xhi (S0-S2);  ws [0,8M): x1 z0/z1 (S4-S7)
    u16* xhi = (u16*)WSK(0);
    u16* x1  = (u16*)WSK(0);          // + z*2097152 elems
    // ws [8,11M): wqh (S1-S2) -> td (S7-): td1 [8,12M), td2 [12,16M)
    u16* wqh = (u16*)WSK(8192);       // + z*786432 elems
    u16* td1 = (u16*)WSK(8192);
    u16* td2 = (u16*)WSK(12288);
    // ws [11,13M): w1h [11,12M), w2h [12,13M) (S1-S6; dead before td writes)
    u16* w1h = (u16*)WSK(11264);      // + z*262144 elems
    u16* w2h = (u16*)WSK(12288);      // + z*262144 elems
    // ws [13,37M): qkvB (S2-S3)
    u16* qkvB = (u16*)WSK(13312);     // [z][4096][1536]
    // ws [24,32M): ffo single bf16 (S6-S7; qkvB dead)
    u16* ffo = (u16*)WSK(24576);      // + z*2097152 elems
    // d_out: AO bf16 (S3-S4) [0,8M); h bf16 (S5-S6) [8,16M); final out (S8)
    u16* AO0 = (u16*)OBK(0);
    u16* AO1 = (u16*)OBK(4096);
    u16* hB  = (u16*)OBK(8192);       // + z*2097152 elems
    float* out = (float*)d_out;

    // S0+S1: merged prep (x convert + 3 weight transposes)
    prep<<<4608, 256, 0, stream>>>(x, xhi,
        wqkv[0], wqkv[1], wqh, w1[0], w1[1], w1h, w2[0], w2[1], w2h);
    // S2: qkv gemm — BM=128 (768 blocks), 1-term, permuted-B
    gemm_mfma<128, 0><<<dim3(32, 12, 2), 256, 0, stream>>>(
        xhi, 0, wqh, 786432, bqkv[0], bqkv[1], 1536,
        qkvB, qkvB);
    // S3: attention (z=0 causal, z=1 anti-causal), QBLK=64, bf16 AO
    attn_mfma<<<dim3(32, 16, 2), 256, 0, stream>>>(qkvB, AO0, AO1);
    // S4: add + LN -> x1 single bf16
    add_ln_a<<<dim3(1024, 1, 2), 256, 0, stream>>>(x, AO0, AO1,
        ga[0], ga[1], bea[0], bea[1], x1, 2097152);
    // S5: ff1 (gelu) -> h bf16 (d_out [8,16M)), BM=64
    gemm_mfma<64, 1><<<dim3(64, 4, 2), 256, 0, stream>>>(
        x1, 2097152, w1h, 262144, b1[0], b1[1], 512,
        hB, hB + 2097152);
    // S6: ff2 -> ffo bf16 (ws), BM=64
    gemm_mfma<64, 2><<<dim3(64, 4, 2), 256, 0, stream>>>(
        hB, 2097152, w2h, 262144, b2[0], b2[1], 512,
        ffo, ffo + 2097152);
    // S7: add + LN + sigmoid -> td
    add_ln_b<<<dim3(1024, 1, 2), 256, 0, stream>>>(
        x1, 2097152, ffo, 2097152,
        gb[0], gb[1], beb[0], beb[1], td1, 2097152);
    // S8: sim (64x128 tiles, 512 blocks)
    sim_mfma<<<dim3(16, 8, 4), 256, 0, stream>>>(td1, td2, out);
}

// Round 21
// 124.752 us; speedup vs baseline: 1.0958x; 1.0074x over previous
//
#include <hip/hip_runtime.h>
#include <math.h>

// ---------------------------------------------------------------------------
// bf16-MFMA implementation, both layers merged (z=2), global_load_lds staging.
//  - all GEMMs 1-term plain bf16; qkv BM=128, FF BM=64 (R17-proven optimum)
//  - attention QBLK=64 (R17-proven), R21: V transpose-stage writes packed as
//    ds_write_b32 (jv-pair per thread) -> bank-conflict-free writeV.
//  - qkv linear [z][4096][1536] output via permuted weight rows (R10)
//  - attention core: R12 att[2] pipeline (swapped QK^T, in-reg P, defer-max,
//    setprio)
// ---------------------------------------------------------------------------

typedef float f32x4 __attribute__((ext_vector_type(4)));
typedef short s16x8 __attribute__((ext_vector_type(8)));
typedef int   i32x4 __attribute__((ext_vector_type(4)));
typedef unsigned short u16;
typedef unsigned int u32;

#define NTOK 1024
#define PL 512
#define QSCALE 0.04419417382415922f  // 1/sqrt(512)

__device__ inline u16 f2bf(float f) {
    unsigned u = __builtin_bit_cast(unsigned, f);
    unsigned r = u + 0x7fffu + ((u >> 16) & 1u);   // RNE
    return (u16)(r >> 16);
}
__device__ inline float bf2f(u16 h) {
    unsigned u = ((unsigned)h) << 16;
    return __builtin_bit_cast(float, u);
}
__device__ inline u32 cvtpk(float a, float b) {   // lo=a, hi=b (RNE)
    u32 r;
    asm("v_cvt_pk_bf16_f32 %0, %1, %2" : "=v"(r) : "v"(a), "v"(b));
    return r;
}

__device__ inline void gll16(const void* g, void* l) {
    __builtin_amdgcn_global_load_lds(
        (const __attribute__((address_space(1))) u32*)g,
        (__attribute__((address_space(3))) u32*)l, 16, 0, 0);
}

// ---------------------------------------------------------------------------
// Merged prep: blockIdx ranges -> {x->bf16, wqkv^T, w1^T, w2^T}
// ---------------------------------------------------------------------------
__global__ __launch_bounds__(256) void prep(const float* __restrict__ X,
    u16* __restrict__ xhi,
    const float* __restrict__ Wq0, const float* __restrict__ Wq1, u16* __restrict__ wqh,
    const float* __restrict__ W10, const float* __restrict__ W11, u16* __restrict__ w1h,
    const float* __restrict__ W20, const float* __restrict__ W21, u16* __restrict__ w2h)
{
    const int bid = blockIdx.x;
    if (bid < 2048) {
        const int i = (bid * 256 + threadIdx.x) * 4;
        float4 v = *(const float4*)&X[i];
        xhi[i + 0] = f2bf(v.x); xhi[i + 1] = f2bf(v.y);
        xhi[i + 2] = f2bf(v.z); xhi[i + 3] = f2bf(v.w);
        return;
    }
    const float* W;
    u16* Whi;
    int N, kx, ny;
    if (bid < 3584) {
        const int idx = bid - 2048;
        const int z = idx / 768, rem = idx % 768;
        kx = rem % 16; ny = rem / 16;
        W = z ? Wq1 : Wq0; Whi = wqh + (size_t)z * 786432; N = 1536;
    } else if (bid < 4096) {
        const int idx = bid - 3584;
        const int z = idx / 256, rem = idx % 256;
        kx = rem % 16; ny = rem / 16;
        W = z ? W11 : W10; Whi = w1h + (size_t)z * 262144; N = 512;
    } else {
        const int idx = bid - 4096;
        const int z = idx / 256, rem = idx % 256;
        kx = rem % 16; ny = rem / 16;
        W = z ? W21 : W20; Whi = w2h + (size_t)z * 262144; N = 512;
    }
    __shared__ float T[32][36];
    const int k0 = kx * 32, n0 = ny * 32;
    const int tr = threadIdx.x >> 3, tc = (threadIdx.x & 7) * 4;
    *(float4*)&T[tr][tc] = *(const float4*)&W[(size_t)(k0 + tr) * N + n0 + tc];
    __syncthreads();
    const size_t o = (size_t)(n0 + tr) * 512 + k0 + tc;
    #pragma unroll
    for (int j = 0; j < 4; j++) Whi[o + j] = f2bf(T[tc + j][tr]);
}

// π: permuted col j -> original col (head-fast split c2 = dd*8+h)
__device__ inline int qkv_perm(int j) {
    return (j >> 9) * 512 + ((j & 63) << 3) + ((j >> 6) & 7);
}

// ---------------------------------------------------------------------------
// 1-term bf16 MFMA GEMM, z = layer. A[4096][512] x Bt[N][512].
// EPI: 0 = qkv (B rows permuted, linear output, Q scaled),
//      1 = gelu -> bf16, 2 = plain bf16.
// BK=32; dbuf gll staging. Wave (wm,wn): rows [wm*BM/2,+BM/2) x cols [wn*64,+64).
// ---------------------------------------------------------------------------
template<int BM, int EPI>
__global__ __launch_bounds__(256) void gemm_mfma(
    const u16* __restrict__ AB, const size_t aLS,
    const u16* __restrict__ BB, const size_t bLS,
    const float* __restrict__ bias0, const float* __restrict__ bias1, const int Ncols,
    u16* __restrict__ oh0, u16* __restrict__ oh1)
{
    constexpr int FM = BM / 32;          // fragments per wave in M
    constexpr int WMS = BM / 2;          // wave M-stride
    __shared__ u16 Ah[2][BM * 32], Bh[2][128 * 32];
    const int z = blockIdx.z;
    const u16* A = AB + (size_t)z * aLS;
    const u16* B = BB + (size_t)z * bLS;
    const float* bias = z ? bias1 : bias0;
    u16* oh = z ? oh1 : oh0;

    const int t = threadIdx.x, l = t & 63, w = t >> 6;
    const int lr = l & 15, lg = l >> 4;
    const int wm = w >> 1, wn = w & 1;
    const int m0 = blockIdx.x * BM, n0 = blockIdx.y * 128;
    const int srow = l >> 2, sch = l & 3;    // staging lane coords (16 rows/KB)

    f32x4 acc[FM][4];
    #pragma unroll
    for (int i = 0; i < FM; i++)
        #pragma unroll
        for (int j = 0; j < 4; j++) acc[i][j] = f32x4{0.f, 0.f, 0.f, 0.f};

    auto stage = [&](int bufi, int k0) {
        for (int j = w; j < BM / 16; j += 4) {
            const int r = j * 16 + srow;
            const int ck = sch ^ ((r >> 1) & 3);
            gll16(&A[(size_t)(m0 + r) * 512 + k0 + ck * 8], &Ah[bufi][j * 512]);
        }
        for (int j = w; j < 8; j += 4) {
            const int r = j * 16 + srow;
            const int ck = sch ^ ((r >> 1) & 3);
            const int brow = (EPI == 0) ? qkv_perm(n0 + r) : (n0 + r);
            gll16(&B[(size_t)brow * 512 + k0 + ck * 8], &Bh[bufi][j * 512]);
        }
    };

    stage(0, 0);
    __syncthreads();
    int buf = 0;
    for (int kt = 0; kt < 16; kt++) {
        if (kt < 15) stage(buf ^ 1, (kt + 1) * 32);

        s16x8 ah[FM];
        #pragma unroll
        for (int fm = 0; fm < FM; fm++) {
            const int r = wm * WMS + fm * 16 + lr;
            ah[fm] = *(const s16x8*)&Ah[buf][r * 32 + ((lg ^ ((r >> 1) & 3)) << 3)];
        }
        #pragma unroll
        for (int fn = 0; fn < 4; fn++) {
            const int r = wn * 64 + fn * 16 + lr;
            s16x8 bh = *(const s16x8*)&Bh[buf][r * 32 + ((lg ^ ((r >> 1) & 3)) << 3)];
            #pragma unroll
            for (int fm = 0; fm < FM; fm++)
                acc[fm][fn] = __builtin_amdgcn_mfma_f32_16x16x32_bf16(ah[fm], bh, acc[fm][fn], 0, 0, 0);
        }
        __syncthreads();   // waves done with buf; stage(buf^1) drained
        buf ^= 1;
    }
    // epilogue: every wave writes its own (wm,wn) sub-tile
    #pragma unroll
    for (int fm = 0; fm < FM; fm++)
        #pragma unroll
        for (int fn = 0; fn < 4; fn++)
            #pragma unroll
            for (int rg = 0; rg < 4; rg++) {
                const int r = m0 + wm * WMS + fm * 16 + lg * 4 + rg;
                const int c = n0 + wn * 64 + fn * 16 + lr;
                if constexpr (EPI == 0) {
                    float v = acc[fm][fn][rg] + bias[qkv_perm(c)];
                    if (c < 512) v *= QSCALE;   // Q third (uniform per block)
                    oh[((size_t)z * 4096 + r) * Ncols + c] = f2bf(v);
                } else {
                    float gl = acc[fm][fn][rg] + bias[c];
                    if constexpr (EPI == 1)
                        gl = 0.5f * gl * (1.f + erff(gl * 0.70710678118654752f));
                    oh[(size_t)r * Ncols + c] = f2bf(gl);
                }
            }
}

// ---------------------------------------------------------------------------
// Flash attention, bf16 MFMA, z = layer (z==0 causal, z==1 anti-causal).
// R12 structure; AO output bf16. QBLK=64, grid (32,16,2).
// R21: V transpose-stage packed as ds_write_b32 (jv-pair per thread).
// ---------------------------------------------------------------------------
__global__ __launch_bounds__(256) void attn_mfma(const u16* __restrict__ QKV,
    u16* __restrict__ AO0, u16* __restrict__ AO1)
{
    __shared__ u16 Ks[2][64 * 64];
    __shared__ u16 Vs[2][64 * 64];
    const int t = threadIdx.x, l = t & 63, w = t >> 6;
    const int lr = l & 15, lg = l >> 4;
    const int z = blockIdx.z;
    const int causal = (z == 0);
    const int bh = blockIdx.x;
    const int b = bh >> 3, h = bh & 7;
    const int qt = causal ? (15 - (int)blockIdx.y) : (int)blockIdx.y;  // long jobs first
    const u16* base = QKV + ((size_t)z * 4096 + (size_t)b * NTOK) * 1536;
    u16* AO = z ? AO1 : AO0;
    const int q0 = qt * 64 + w * 16;

    s16x8 aq[2];
    aq[0] = *(const s16x8*)&base[(size_t)(q0 + lr) * 1536 + h * 64 + lg * 8];
    aq[1] = *(const s16x8*)&base[(size_t)(q0 + lr) * 1536 + h * 64 + 32 + lg * 8];

    f32x4 o[4];
    float m_ = -INFINITY, l_ = 0.f;
    #pragma unroll
    for (int f = 0; f < 4; f++) o[f] = f32x4{0.f, 0.f, 0.f, 0.f};

    const int kt0 = causal ? 0 : qt, kt1 = causal ? qt : 15;

    auto stageK = [&](int kt) {
        #pragma unroll
        for (int i = 0; i < 2; i++) {
            const int j = w * 2 + i;
            const int r = j * 8 + (l >> 3);
            const int ck = (l & 7) ^ (r & 7);
            gll16(&base[(size_t)(kt * 64 + r) * 1536 + 512 + h * 64 + ck * 8],
                  &Ks[kt & 1][j * 512]);
        }
    };
    // V tile: thread owns jv pair {2mv, 2mv+1} x 8 dims dv..dv+7
    const int mv = l & 31;
    const int dv = w * 16 + ((l >> 5) << 3);
    s16x8 va, vb;
    auto loadV = [&](int kt) {
        const u16* vr = &base[(size_t)(kt * 64 + 2 * mv) * 1536 + 1024 + h * 64 + dv];
        va = *(const s16x8*)vr;
        vb = *(const s16x8*)(vr + 1536);
    };
    auto writeV = [&](int kt) {
        #pragma unroll
        for (int i = 0; i < 8; i++) {
            const int d = dv + i;
            const int idx = d * 64 + (((mv >> 2) ^ (d & 7)) << 3) + ((mv & 3) << 1);
            *(u32*)&Vs[kt & 1][idx] =
                (u32)(u16)va[i] | ((u32)(u16)vb[i] << 16);
        }
    };

    s16x8 pap[2];
    float psc[4] = {1.f, 1.f, 1.f, 1.f};
    int pneed = 1;

    auto QK = [&](int kt, f32x4* s) {
        #pragma unroll
        for (int f = 0; f < 4; f++) s[f] = f32x4{0.f, 0.f, 0.f, 0.f};
        #pragma unroll
        for (int kk = 0; kk < 2; kk++)
            #pragma unroll
            for (int f = 0; f < 4; f++) {
                const int row = f * 16 + lr;
                const int ch = kk * 4 + lg;
                s16x8 bk = *(const s16x8*)&Ks[kt & 1][row * 64 + ((ch ^ (row & 7)) << 3)];
                s[f] = __builtin_amdgcn_mfma_f32_16x16x32_bf16(bk, aq[kk], s[f], 0, 0, 0);
            }
        if (kt == qt) {
            const int q = q0 + lr;
            #pragma unroll
            for (int f = 0; f < 4; f++)
                #pragma unroll
                for (int r = 0; r < 4; r++) {
                    const int key = kt * 64 + f * 16 + lg * 4 + r;
                    if (causal ? (key > q) : (key < q)) s[f][r] = -INFINITY;
                }
        }
    };

    auto SM = [&](f32x4* s) {
        float rm = s[0][0];
        #pragma unroll
        for (int f = 0; f < 4; f++)
            #pragma unroll
            for (int r = 0; r < 4; r++) rm = fmaxf(rm, s[f][r]);
        rm = fmaxf(rm, __shfl_xor(rm, 16));
        rm = fmaxf(rm, __shfl_xor(rm, 32));
        pneed = !__all(rm <= m_ + 8.f);          // defer-max (T13)
        const float mn = pneed ? fmaxf(m_, rm) : m_;
        const float sc = __expf(m_ - mn);        // ==1 when deferred
        float ps = 0.f;
        #pragma unroll
        for (int f = 0; f < 4; f++)
            #pragma unroll
            for (int r = 0; r < 4; r++) {
                float p = __expf(s[f][r] - mn);
                s[f][r] = p;
                ps += p;
            }
        ps += __shfl_xor(ps, 16);
        ps += __shfl_xor(ps, 32);
        l_ = l_ * sc + ps;
        m_ = mn;
        u32 P01[4], P23[4];
        #pragma unroll
        for (int f = 0; f < 4; f++) {
            P01[f] = cvtpk(s[f][0], s[f][1]);
            P23[f] = cvtpk(s[f][2], s[f][3]);
        }
        const int srcA = lr + ((lg & 1) << 5);
        const int srcB = srcA + 16;
        #pragma unroll
        for (int kk = 0; kk < 2; kk++) {
            const u32 a01_0 = (u32)__shfl((int)P01[2 * kk], srcA);
            const u32 a01_1 = (u32)__shfl((int)P01[2 * kk + 1], srcA);
            const u32 a23_0 = (u32)__shfl((int)P23[2 * kk], srcA);
            const u32 a23_1 = (u32)__shfl((int)P23[2 * kk + 1], srcA);
            const u32 b01_0 = (u32)__shfl((int)P01[2 * kk], srcB);
            const u32 b01_1 = (u32)__shfl((int)P01[2 * kk + 1], srcB);
            const u32 b23_0 = (u32)__shfl((int)P23[2 * kk], srcB);
            const u32 b23_1 = (u32)__shfl((int)P23[2 * kk + 1], srcB);
            i32x4 av;
            av[0] = (int)((lg & 2) ? a01_1 : a01_0);
            av[1] = (int)((lg & 2) ? a23_1 : a23_0);
            av[2] = (int)((lg & 2) ? b01_1 : b01_0);
            av[3] = (int)((lg & 2) ? b23_1 : b23_0);
            pap[kk] = __builtin_bit_cast(s16x8, av);
        }
        if (pneed) {
            #pragma unroll
            for (int r = 0; r < 4; r++) psc[r] = __shfl(sc, lg * 4 + r);
        }
    };

    auto PV = [&](int kt) {
        if (pneed) {
            #pragma unroll
            for (int r = 0; r < 4; r++)
                #pragma unroll
                for (int f = 0; f < 4; f++) o[f][r] *= psc[r];
        }
        #pragma unroll
        for (int kk = 0; kk < 2; kk++)
            #pragma unroll
            for (int f = 0; f < 4; f++) {
                const int row = f * 16 + lr;
                const int ch = kk * 4 + lg;
                s16x8 bv = *(const s16x8*)&Vs[kt & 1][row * 64 + ((ch ^ (row & 7)) << 3)];
                o[f] = __builtin_amdgcn_mfma_f32_16x16x32_bf16(pap[kk], bv, o[f], 0, 0, 0);
            }
    };

    // ---- prologue ----
    stageK(kt0);
    if (kt0 < kt1) stageK(kt0 + 1);
    loadV(kt0);
    writeV(kt0);
    __syncthreads();
    {
        f32x4 s0[4];
        QK(kt0, s0);
        SM(s0);
    }
    __syncthreads();

    // ---- main loop: QK(t+1) -> PV(t) -> SM(t+1) ----
    for (int kt = kt0; kt <= kt1; kt++) {
        if (kt + 2 <= kt1) stageK(kt + 2);
        if (kt + 1 <= kt1) loadV(kt + 1);
        f32x4 sn[4];
        __builtin_amdgcn_s_setprio(1);
        if (kt + 1 <= kt1) QK(kt + 1, sn);
        PV(kt);
        __builtin_amdgcn_s_setprio(0);
        if (kt + 1 <= kt1) {
            SM(sn);
            writeV(kt + 1);
        }
        __syncthreads();
    }

    // ---- epilogue: bf16 AO, head-slow merge ----
    const float linv = 1.f / l_;
    #pragma unroll
    for (int r = 0; r < 4; r++) {
        const float lv = __shfl(linv, lg * 4 + r);
        #pragma unroll
        for (int f = 0; f < 4; f++)
            AO[(size_t)(b * NTOK + q0 + lg * 4 + r) * PL + h * 64 + f * 16 + lr] =
                f2bf(o[f][r] * lv);
    }
}

// ---------------------------------------------------------------------------
// add+LN A: x(f32)+attn(bf16) -> LN -> single bf16 x1. z = layer.
// ---------------------------------------------------------------------------
__global__ __launch_bounds__(256) void add_ln_a(const float* __restrict__ X,
    const u16* __restrict__ A0, const u16* __restrict__ A1,
    const float* __restrict__ g0, const float* __restrict__ g1,
    const float* __restrict__ be0, const float* __restrict__ be1,
    u16* __restrict__ OB, const size_t oLS)
{
    const int z = blockIdx.z;
    const u16* A = z ? A1 : A0;
    const float* g = z ? g1 : g0;
    const float* be = z ? be1 : be0;
    u16* O = OB + (size_t)z * oLS;
    const int row = blockIdx.x * 4 + (threadIdx.x >> 6);
    const int lane = threadIdx.x & 63;
    const float* xr = X + (size_t)row * PL;
    const u16* ar = A + (size_t)row * PL;
    float v[8];
    float sum = 0.f;
    #pragma unroll
    for (int u = 0; u < 8; u++) { v[u] = xr[lane + u * 64] + bf2f(ar[lane + u * 64]); sum += v[u]; }
    #pragma unroll
    for (int o = 32; o > 0; o >>= 1) sum += __shfl_xor(sum, o);
    const float mu = sum * (1.f / 512.f);
    float s2 = 0.f;
    #pragma unroll
    for (int u = 0; u < 8; u++) { float d = v[u] - mu; s2 = fmaf(d, d, s2); }
    #pragma unroll
    for (int o = 32; o > 0; o >>= 1) s2 += __shfl_xor(s2, o);
    const float rstd = rsqrtf(s2 * (1.f / 512.f) + 1e-5f);
    #pragma unroll
    for (int u = 0; u < 8; u++) {
        const int c = lane + u * 64;
        O[(size_t)row * PL + c] = f2bf((v[u] - mu) * rstd * g[c] + be[c]);
    }
}

// ---------------------------------------------------------------------------
// add+LN B: x1(bf16) + ffo(bf16) -> LN -> sigmoid -> bf16 td. z = layer.
// ---------------------------------------------------------------------------
__global__ __launch_bounds__(256) void add_ln_b(
    const u16* __restrict__ X1B, const size_t xLS,
    const u16* __restrict__ FB, const size_t fLS,
    const float* __restrict__ g0, const float* __restrict__ g1,
    const float* __restrict__ be0, const float* __restrict__ be1,
    u16* __restrict__ TDB, const size_t tLS)
{
    const int z = blockIdx.z;
    const u16* X1 = X1B + (size_t)z * xLS;
    const u16* F = FB + (size_t)z * fLS;
    const float* g = z ? g1 : g0;
    const float* be = z ? be1 : be0;
    u16* TD = TDB + (size_t)z * tLS;
    const int row = blockIdx.x * 4 + (threadIdx.x >> 6);
    const int lane = threadIdx.x & 63;
    const size_t ro = (size_t)row * PL;
    float v[8];
    float sum = 0.f;
    #pragma unroll
    for (int u = 0; u < 8; u++) {
        const int c = lane + u * 64;
        v[u] = bf2f(X1[ro + c]) + bf2f(F[ro + c]);
        sum += v[u];
    }
    #pragma unroll
    for (int o = 32; o > 0; o >>= 1) sum += __shfl_xor(sum, o);
    const float mu = sum * (1.f / 512.f);
    float s2 = 0.f;
    #pragma unroll
    for (int u = 0; u < 8; u++) { float d = v[u] - mu; s2 = fmaf(d, d, s2); }
    #pragma unroll
    for (int o = 32; o > 0; o >>= 1) s2 += __shfl_xor(s2, o);
    const float rstd = rsqrtf(s2 * (1.f / 512.f) + 1e-5f);
    #pragma unroll
    for (int u = 0; u < 8; u++) {
        const int c = lane + u * 64;
        float y = (v[u] - mu) * rstd * g[c] + be[c];
        TD[ro + c] = f2bf(1.f / (1.f + expf(-y)));
    }
}

// ---------------------------------------------------------------------------
// sim: per batch, C[i][j] = dot(td1[i,:], td2[j,:]) / 512  (plain bf16 MFMA)
// 64x128 tiles -> 512 blocks. gll-staged, BK=64, dbuf.
// ---------------------------------------------------------------------------
__global__ __launch_bounds__(256) void sim_mfma(const u16* __restrict__ TD1,
    const u16* __restrict__ TD2, float* __restrict__ Out)
{
    __shared__ u16 Ah[2][64 * 64], Bh[2][128 * 64];
    const int t = threadIdx.x, l = t & 63, w = t >> 6;
    const int lr = l & 15, lg = l >> 4;
    const int wm = w >> 1, wn = w & 1;
    const int bz = blockIdx.z;
    const u16* A = TD1 + (size_t)bz * NTOK * PL;
    const u16* B = TD2 + (size_t)bz * NTOK * PL;
    const int m0 = blockIdx.x * 64, n0 = blockIdx.y * 128;

    f32x4 acc[2][4];
    #pragma unroll
    for (int i = 0; i < 2; i++)
        #pragma unroll
        for (int j = 0; j < 4; j++) acc[i][j] = f32x4{0.f, 0.f, 0.f, 0.f};

    auto stage = [&](int bufi, int k0) {
        #pragma unroll
        for (int i = 0; i < 2; i++) {
            const int j = w * 2 + i;
            const int r = j * 8 + (l >> 3);
            const int ck = (l & 7) ^ (r & 7);
            gll16(&A[(size_t)(m0 + r) * 512 + k0 + ck * 8], &Ah[bufi][j * 512]);
        }
        #pragma unroll
        for (int i = 0; i < 4; i++) {
            const int j = w * 4 + i;
            const int r = j * 8 + (l >> 3);
            const int ck = (l & 7) ^ (r & 7);
            gll16(&B[(size_t)(n0 + r) * 512 + k0 + ck * 8], &Bh[bufi][j * 512]);
        }
    };

    stage(0, 0);
    __syncthreads();
    int buf = 0;
    for (int kt = 0; kt < 8; kt++) {
        if (kt < 7) stage(buf ^ 1, (kt + 1) * 64);
        #pragma unroll
        for (int kk = 0; kk < 2; kk++) {
            const int ch = kk * 4 + lg;
            s16x8 af[2], bf[4];
            #pragma unroll
            for (int fm = 0; fm < 2; fm++) {
                const int r = wm * 32 + fm * 16 + lr;
                af[fm] = *(const s16x8*)&Ah[buf][r * 64 + ((ch ^ (r & 7)) << 3)];
            }
            #pragma unroll
            for (int fn = 0; fn < 4; fn++) {
                const int r = wn * 64 + fn * 16 + lr;
                bf[fn] = *(const s16x8*)&Bh[buf][r * 64 + ((ch ^ (r & 7)) << 3)];
            }
            #pragma unroll
            for (int fm = 0; fm < 2; fm++)
                #pragma unroll
                for (int fn = 0; fn < 4; fn++)
                    acc[fm][fn] = __builtin_amdgcn_mfma_f32_16x16x32_bf16(af[fm], bf[fn], acc[fm][fn], 0, 0, 0);
        }
        __syncthreads();
        buf ^= 1;
    }
    #pragma unroll
    for (int fm = 0; fm < 2; fm++)
        #pragma unroll
        for (int fn = 0; fn < 4; fn++)
            #pragma unroll
            for (int rg = 0; rg < 4; rg++) {
                const int r = m0 + wm * 32 + fm * 16 + lg * 4 + rg;
                const int c = n0 + wn * 64 + fn * 16 + lr;
                Out[((size_t)(bz * NTOK + r)) * NTOK + c] = acc[fm][fn][rg] * (1.f / 512.f);
            }
}

// ---------------------------------------------------------------------------
extern "C" void kernel_launch(void* const* d_in, const int* in_sizes, int n_in,
                              void* d_out, int out_size, void* d_ws, size_t ws_size,
                              hipStream_t stream)
{
    const float* x = (const float*)d_in[0];
    const float* wqkv[2] = {(const float*)d_in[1],  (const float*)d_in[11]};
    const float* bqkv[2] = {(const float*)d_in[2],  (const float*)d_in[12]};
    const float* ga[2]   = {(const float*)d_in[3],  (const float*)d_in[13]};
    const float* bea[2]  = {(const float*)d_in[4],  (const float*)d_in[14]};
    const float* w1[2]   = {(const float*)d_in[5],  (const float*)d_in[15]};
    const float* b1[2]   = {(const float*)d_in[6],  (const float*)d_in[16]};
    const float* w2[2]   = {(const float*)d_in[7],  (const float*)d_in[17]};
    const float* b2[2]   = {(const float*)d_in[8],  (const float*)d_in[18]};
    const float* gb[2]   = {(const float*)d_in[9],  (const float*)d_in[19]};
    const float* beb[2]  = {(const float*)d_in[10], (const float*)d_in[20]};

    // -------- workspace map (KB offsets; lifetimes verified stage-by-stage) --
    char* wsb = (char*)d_ws;
    char* ob  = (char*)d_out;
    #define WSK(kb) ((char*)wsb + ((size_t)(kb) << 10))
    #define OBK(kb) ((char*)ob  + ((size_t)(kb) << 10))
    // ws [0,4M):  xhi (S0-S2);  ws [0,8M): x1 z0/z1 (S4-S7)
    u16* xhi = (u16*)WSK(0);
    u16* x1  = (u16*)WSK(0);          // + z*2097152 elems
    // ws [8,11M): wqh (S1-S2) -> td (S7-): td1 [8,12M), td2 [12,16M)
    u16* wqh = (u16*)WSK(8192);       // + z*786432 elems
    u16* td1 = (u16*)WSK(8192);
    u16* td2 = (u16*)WSK(12288);
    // ws [11,13M): w1h [11,12M), w2h [12,13M) (S1-S6; dead before td writes)
    u16* w1h = (u16*)WSK(11264);      // + z*262144 elems
    u16* w2h = (u16*)WSK(12288);      // + z*262144 elems
    // ws [13,37M): qkvB (S2-S3)
    u16* qkvB = (u16*)WSK(13312);     // [z][4096][1536]
    // ws [24,32M): ffo single bf16 (S6-S7; qkvB dead)
    u16* ffo = (u16*)WSK(24576);      // + z*2097152 elems
    // d_out: AO bf16 (S3-S4) [0,8M); h bf16 (S5-S6) [8,16M); final out (S8)
    u16* AO0 = (u16*)OBK(0);
    u16* AO1 = (u16*)OBK(4096);
    u16* hB  = (u16*)OBK(8192);       // + z*2097152 elems
    float* out = (float*)d_out;

    // S0+S1: merged prep (x convert + 3 weight transposes)
    prep<<<4608, 256, 0, stream>>>(x, xhi,
        wqkv[0], wqkv[1], wqh, w1[0], w1[1], w1h, w2[0], w2[1], w2h);
    // S2: qkv gemm — BM=128 (768 blocks), 1-term, permuted-B
    gemm_mfma<128, 0><<<dim3(32, 12, 2), 256, 0, stream>>>(
        xhi, 0, wqh, 786432, bqkv[0], bqkv[1], 1536,
        qkvB, qkvB);
    // S3: attention (z=0 causal, z=1 anti-causal), QBLK=64, bf16 AO
    attn_mfma<<<dim3(32, 16, 2), 256, 0, stream>>>(qkvB, AO0, AO1);
    // S4: add + LN -> x1 single bf16
    add_ln_a<<<dim3(1024, 1, 2), 256, 0, stream>>>(x, AO0, AO1,
        ga[0], ga[1], bea[0], bea[1], x1, 2097152);
    // S5: ff1 (gelu) -> h bf16 (d_out [8,16M)), BM=64
    gemm_mfma<64, 1><<<dim3(64, 4, 2), 256, 0, stream>>>(
        x1, 2097152, w1h, 262144, b1[0], b1[1], 512,
        hB, hB + 2097152);
    // S6: ff2 -> ffo bf16 (ws), BM=64
    gemm_mfma<64, 2><<<dim3(64, 4, 2), 256, 0, stream>>>(
        hB, 2097152, w2h, 262144, b2[0], b2[1], 512,
        ffo, ffo + 2097152);
    // S7: add + LN + sigmoid -> td
    add_ln_b<<<dim3(1024, 1, 2), 256, 0, stream>>>(
        x1, 2097152, ffo, 2097152,
        gb[0], gb[1], beb[0], beb[1], td1, 2097152);
    // S8: sim (64x128 tiles, 512 blocks)
    sim_mfma<<<dim3(16, 8, 4), 256, 0, stream>>>(td1, td2, out);
}